// Round 1
// baseline (255.920 us; speedup 1.0000x reference)
//
#include <hip/hip_runtime.h>
#include <hip/hip_bf16.h>

// AttentionSeparateQKV: B=16 N=1024 D=768 H=12 HD=64, V = K-projection (reference bug kept).
// Pipeline: cvt(x,W*)->bf16 | q,k = bf16 MFMA GEMM (+bias) | flash attn (swapped-QK 32x32 mfma,
// online softmax) | out = bf16 MFMA GEMM (+bias) in fp32.

#define DEV static __device__ __forceinline__

typedef __attribute__((ext_vector_type(8)))  short  short8;
typedef __attribute__((ext_vector_type(4)))  short  short4v;
typedef __attribute__((ext_vector_type(4)))  float  f32x4;
typedef __attribute__((ext_vector_type(16))) float  f32x16;
typedef __attribute__((ext_vector_type(4)))  unsigned short ushort4v;

DEV unsigned short f2bf(float x) {
  unsigned int u = __float_as_uint(x);
  u = u + 0x7fffu + ((u >> 16) & 1u);   // RNE, inputs finite
  return (unsigned short)(u >> 16);
}

#define GLOAD_LDS16(g, l)                                                     \
  __builtin_amdgcn_global_load_lds(                                           \
      (const __attribute__((address_space(1))) void*)(g),                     \
      (__attribute__((address_space(3))) void*)(l), 16, 0, 0)

// ---------------- fp32 -> bf16 convert, 4 elems/thread ----------------
__global__ __launch_bounds__(256) void k_cvt(const float* __restrict__ src,
                                             unsigned short* __restrict__ dst,
                                             int n4) {
  int i = blockIdx.x * 256 + threadIdx.x;
  if (i >= n4) return;
  f32x4 v = *(const f32x4*)(src + (size_t)i * 4);
  ushort4v o;
  o[0] = f2bf(v[0]); o[1] = f2bf(v[1]); o[2] = f2bf(v[2]); o[3] = f2bf(v[3]);
  *(ushort4v*)(dst + (size_t)i * 4) = o;
}

// ---------------- GEMM: C[M,N] = A[M,K] * W[N,K]^T + bias[N] ----------------
// 128x128 tile, BK=64, 256 threads (4 waves 2x2, each 64x64 = 4x4 frags of 16x16x32).
// global_load_lds(16B) staging, XOR swizzle (byte ^= (row&7)<<4) applied on the
// global SOURCE address (LDS written linearly) and on the ds_read address.
template <int OUT_BF16>
__global__ __launch_bounds__(256) void k_gemm_bt(const unsigned short* __restrict__ A,
                                                 const unsigned short* __restrict__ W,
                                                 const float* __restrict__ bias,
                                                 void* __restrict__ Cv,
                                                 int M, int N, int K) {
  __shared__ char lds[32768];
  char* ldsA = lds;
  char* ldsB = lds + 16384;
  const int tid  = threadIdx.x;
  const int wid  = tid >> 6;
  const int lane = tid & 63;
  const int row0 = blockIdx.x * 128;
  const int col0 = blockIdx.y * 128;
  const int wr = (wid >> 1) * 64;
  const int wc = (wid & 1) * 64;
  const int lr = lane & 15;
  const int lg = lane >> 4;

  f32x4 acc[4][4];
#pragma unroll
  for (int m = 0; m < 4; ++m)
#pragma unroll
    for (int n = 0; n < 4; ++n)
#pragma unroll
      for (int r = 0; r < 4; ++r) acc[m][n][r] = 0.f;

  for (int kt = 0; kt < K; kt += 64) {
    __syncthreads();
#pragma unroll
    for (int p = 0; p < 4; ++p) {
      int blkbase = (p * 4 + wid);            // 1KB block id
      int chunk = blkbase * 64 + lane;        // 16B chunk id, 0..1023
      int r  = chunk >> 3;                    // tile row 0..127
      int cb = ((chunk & 7) << 4) ^ ((r & 7) << 4);  // swizzled byte col in [0,128)
      const char* ga = (const char*)(A + (size_t)(row0 + r) * K + kt) + cb;
      GLOAD_LDS16(ga, ldsA + blkbase * 1024);
      const char* gb = (const char*)(W + (size_t)(col0 + r) * K + kt) + cb;
      GLOAD_LDS16(gb, ldsB + blkbase * 1024);
    }
    asm volatile("s_waitcnt vmcnt(0)" ::: "memory");
    __syncthreads();
#pragma unroll
    for (int kk = 0; kk < 2; ++kk) {
      short8 af[4], bf[4];
#pragma unroll
      for (int m = 0; m < 4; ++m) {
        int row = wr + m * 16 + lr;
        int a   = row * 128 + ((kk * 64 + lg * 16) ^ ((row & 7) << 4));
        af[m] = *(const short8*)(ldsA + a);
        int col = wc + m * 16 + lr;
        int b   = col * 128 + ((kk * 64 + lg * 16) ^ ((col & 7) << 4));
        bf[m] = *(const short8*)(ldsB + b);
      }
#pragma unroll
      for (int m = 0; m < 4; ++m)
#pragma unroll
        for (int n = 0; n < 4; ++n)
          acc[m][n] = __builtin_amdgcn_mfma_f32_16x16x32_bf16(af[m], bf[n], acc[m][n], 0, 0, 0);
    }
  }

  const int r0g = row0 + wr + lg * 4;
  const int c0g = col0 + wc + lr;
  float bv[4];
#pragma unroll
  for (int n = 0; n < 4; ++n) bv[n] = bias[c0g + n * 16];
#pragma unroll
  for (int m = 0; m < 4; ++m)
#pragma unroll
    for (int n = 0; n < 4; ++n)
#pragma unroll
      for (int r = 0; r < 4; ++r) {
        float v = acc[m][n][r] + bv[n];
        size_t off = (size_t)(r0g + m * 16 + r) * N + (c0g + n * 16);
        if constexpr (OUT_BF16) ((unsigned short*)Cv)[off] = f2bf(v);
        else                    ((float*)Cv)[off] = v;
      }
}

// ---------------- Flash attention (V = K) ----------------
// grid: 1536 = (B*H=192) * (N/128). Block 256 = 4 waves; wave w owns 32 q-rows.
// S^T = mfma_32x32x16(K_tile, Q^T): lane owns q=lane&31, 16 of 32 k per tile half.
// O^T = mfma_32x32x16(V^T, P^T): rescale/normalize are lane-scalar in q.
__global__ __launch_bounds__(256) void k_attn(const unsigned short* __restrict__ qg,
                                              const unsigned short* __restrict__ kg,
                                              unsigned short* __restrict__ og) {
  __shared__ char alds[4 * 32 * 144];   // per-wave [32 q][72 bf16] (144B rows)
  const int tid  = threadIdx.x;
  const int w    = tid >> 6;
  const int lane = tid & 63;
  const int q32  = lane & 31;
  const int hi   = lane >> 5;
  const int blk  = blockIdx.x;
  const int qc   = blk & 7;
  const int bh   = blk >> 3;
  const int h = bh % 12, b = bh / 12;
  const int qbase = qc * 128 + w * 32;

  const unsigned short* Qp = qg + (size_t)(b * 1024 + qbase + q32) * 768 + h * 64;
  const unsigned short* Kh = kg + (size_t)(b * 1024) * 768 + h * 64;

  short8 qf[4];
#pragma unroll
  for (int c = 0; c < 4; ++c) qf[c] = *(const short8*)(Qp + c * 16 + hi * 8);

  float mrow = -__builtin_inff();
  float lsum = 0.f;
  f32x16 o0, o1;
#pragma unroll
  for (int r = 0; r < 16; ++r) { o0[r] = 0.f; o1[r] = 0.f; }

  for (int kt = 0; kt < 1024; kt += 32) {
    const unsigned short* Kp = Kh + (size_t)(kt + q32) * 768;
    f32x16 s;
#pragma unroll
    for (int r = 0; r < 16; ++r) s[r] = 0.f;
#pragma unroll
    for (int c = 0; c < 4; ++c) {
      short8 kf = *(const short8*)(Kp + c * 16 + hi * 8);
      s = __builtin_amdgcn_mfma_f32_32x32x16_bf16(kf, qf[c], s, 0, 0, 0);
    }
    // online softmax (q-row state duplicated on lanes q and q+32)
    float tmax = s[0];
#pragma unroll
    for (int r = 1; r < 16; ++r) tmax = fmaxf(tmax, s[r]);
    tmax *= 0.125f;
    tmax = fmaxf(tmax, __shfl_xor(tmax, 32));
    float mnew = fmaxf(mrow, tmax);
    float corr = __expf(mrow - mnew);
    float p[16], ps = 0.f;
#pragma unroll
    for (int r = 0; r < 16; ++r) { p[r] = __expf(s[r] * 0.125f - mnew); ps += p[r]; }
    ps += __shfl_xor(ps, 32);
    lsum = lsum * corr + ps;
    mrow = mnew;
#pragma unroll
    for (int r = 0; r < 16; ++r) { o0[r] *= corr; o1[r] *= corr; }

#pragma unroll
    for (int s2 = 0; s2 < 2; ++s2) {
      // P^T B-frag: lane needs P[q][k], k = s2*16 + hi*8 + j.
      // j<4 lives on lower lane (group 2s2+hi), j>=4 on upper lane (same group).
      short8 pf;
#pragma unroll
      for (int i = 0; i < 4; ++i) {
        float a0 = p[8 * s2 + i];        // own group 2s2
        float a1 = p[8 * s2 + 4 + i];    // own group 2s2+1
        float own = hi ? a1 : a0;        // group 2s2+hi
        float snd = hi ? a0 : a1;        // group 2s2+(1-hi), what partner needs
        float rcv = __shfl_xor(snd, 32); // partner's group 2s2+hi
        float lov = hi ? rcv : own;      // j = i    (from lower lane)
        float hvv = hi ? own : rcv;      // j = 4+i  (from upper lane)
        pf[i]     = (short)f2bf(lov);
        pf[4 + i] = (short)f2bf(hvv);
      }
      // V^T A-frags: lane holds V[k = kt+s2*16+hi*8+j][hd = f*32 + q32]
      const unsigned short* Vp = Kh + (size_t)(kt + s2 * 16 + hi * 8) * 768 + q32;
      short8 vf0, vf1;
#pragma unroll
      for (int j = 0; j < 8; ++j) {
        vf0[j] = (short)Vp[(size_t)j * 768];
        vf1[j] = (short)Vp[(size_t)j * 768 + 32];
      }
      o0 = __builtin_amdgcn_mfma_f32_32x32x16_bf16(vf0, pf, o0, 0, 0, 0);
      o1 = __builtin_amdgcn_mfma_f32_32x32x16_bf16(vf1, pf, o1, 0, 0, 0);
    }
  }

  // epilogue: normalize, transpose via LDS, coalesced 16B stores
  float inv = 1.f / lsum;
  char* lw = alds + w * 4608;
#pragma unroll
  for (int mg = 0; mg < 4; ++mg) {
    short4v t;
#pragma unroll
    for (int i = 0; i < 4; ++i) t[i] = (short)f2bf(o0[mg * 4 + i] * inv);
    *(short4v*)(lw + q32 * 144 + mg * 16 + hi * 8) = t;
#pragma unroll
    for (int i = 0; i < 4; ++i) t[i] = (short)f2bf(o1[mg * 4 + i] * inv);
    *(short4v*)(lw + q32 * 144 + 64 + mg * 16 + hi * 8) = t;
  }
  __syncthreads();
  const size_t obase = (size_t)(b * 1024 + qbase) * 768 + h * 64;
#pragma unroll
  for (int pp = 0; pp < 4; ++pp) {
    int chunk = pp * 64 + lane;      // 0..255
    int qr = chunk >> 3, cc = chunk & 7;
    short8 v = *(const short8*)(lw + qr * 144 + cc * 16);
    *(short8*)(og + obase + (size_t)qr * 768 + cc * 8) = v;
  }
}

// ---------------- launch ----------------
extern "C" void kernel_launch(void* const* d_in, const int* in_sizes, int n_in,
                              void* d_out, int out_size, void* d_ws, size_t ws_size,
                              hipStream_t stream) {
  const float* x  = (const float*)d_in[0];
  const float* Wq = (const float*)d_in[1];
  const float* bq = (const float*)d_in[2];
  const float* Wk = (const float*)d_in[3];
  const float* bk = (const float*)d_in[4];
  const float* Wp = (const float*)d_in[5];
  const float* bp = (const float*)d_in[6];
  float* out = (float*)d_out;
  char* ws = (char*)d_ws;

  const size_t XB = (size_t)16384 * 768 * 2;  // 25,165,824
  const size_t WB = (size_t)768 * 768 * 2;    //  1,179,648
  if (ws_size < 3 * XB + 3 * WB) return;      // leaves d_out poisoned -> visible failure

  unsigned short* xb  = (unsigned short*)(ws);
  unsigned short* qb  = (unsigned short*)(ws + XB);
  unsigned short* kb  = (unsigned short*)(ws + 2 * XB);
  unsigned short* wqb = (unsigned short*)(ws + 3 * XB);
  unsigned short* wkb = (unsigned short*)(ws + 3 * XB + WB);
  unsigned short* wpb = (unsigned short*)(ws + 3 * XB + 2 * WB);
  unsigned short* ab  = xb;  // x no longer needed once q,k exist

  k_cvt<<<12288, 256, 0, stream>>>(x, xb, 16384 * 768 / 4);
  k_cvt<<<576, 256, 0, stream>>>(Wq, wqb, 768 * 768 / 4);
  k_cvt<<<576, 256, 0, stream>>>(Wk, wkb, 768 * 768 / 4);
  k_cvt<<<576, 256, 0, stream>>>(Wp, wpb, 768 * 768 / 4);

  dim3 gg(128, 6);
  k_gemm_bt<1><<<gg, 256, 0, stream>>>(xb, wqb, bq, qb, 16384, 768, 768);
  k_gemm_bt<1><<<gg, 256, 0, stream>>>(xb, wkb, bk, kb, 16384, 768, 768);
  k_attn<<<1536, 256, 0, stream>>>(qb, kb, ab);
  k_gemm_bt<0><<<gg, 256, 0, stream>>>(ab, wpb, bp, out, 16384, 768, 768);
}